// Round 5
// baseline (1275.253 us; speedup 1.0000x reference)
//
#include <hip/hip_runtime.h>

// GAT (2-layer) on MI355X — full-CSR formulation, cooperative row reads,
// wave-cooperative GEMM (coalesced loads/stores, W in registers).
// Closed-form segment softmax: alpha in {+t,-t}; per-src s: p=#pos out-edges,
// deg=out-degree (incl self-loop).
//   w = (flag?1:c) * dinv[s],  dinv = p>0 ? 1/(p+(deg-p)c) : 1/(c*deg).
// edge_index arrives as int32 (harness converts integer inputs).
#define EXPC 0.13533528323661270f  // exp(-2*1.0)

__global__ void zero_i32(int* __restrict__ p, int n) {
  int i = blockIdx.x * blockDim.x + threadIdx.x;
  if (i < n) p[i] = 0;
}

// h[N, DOUT] = (RELU_IN ? relu(x) : x)[N,64] @ W[DOUT,64]^T.
// One wave per 4 rows. Lane l: owns output col c = l % DOUT, holds W[c][0:64]
// in 64 VGPRs. The 4 rows (256 floats) are loaded as one coalesced float4 per
// lane and distributed via __shfl. Stores are contiguous per wave.
template <int DOUT, bool RELU_IN>
__global__ void gemm_k(const float* __restrict__ x, const float* __restrict__ W,
                       float* __restrict__ h, int N) {
  int gtid = blockIdx.x * 256 + threadIdx.x;
  int wave = gtid >> 6;
  int lane = threadIdx.x & 63;
  int r0 = wave * 4;
  if (r0 >= N) return;
  const int c = lane % DOUT;
  float4 Wr[16];
#pragma unroll
  for (int i = 0; i < 16; i++) Wr[i] = *(const float4*)(W + c * 64 + i * 4);

  // load 4 rows: lane covers row r0 + lane/16, 16B chunk (lane%16)
  float4 xv = make_float4(0.f, 0.f, 0.f, 0.f);
  if (r0 + (lane >> 4) < N) {
    xv = *(const float4*)(x + (size_t)r0 * 64 + lane * 4);
    if (RELU_IN) {
      xv.x = fmaxf(xv.x, 0.f); xv.y = fmaxf(xv.y, 0.f);
      xv.z = fmaxf(xv.z, 0.f); xv.w = fmaxf(xv.w, 0.f);
    }
  }

  if (DOUT == 64) {
    float acc[4] = {0.f, 0.f, 0.f, 0.f};
#pragma unroll
    for (int r = 0; r < 4; r++) {
#pragma unroll
      for (int i = 0; i < 16; i++) {
        int src = r * 16 + i;
        float ax = __shfl(xv.x, src);
        float ay = __shfl(xv.y, src);
        float az = __shfl(xv.z, src);
        float aw = __shfl(xv.w, src);
        acc[r] = fmaf(ax, Wr[i].x, fmaf(ay, Wr[i].y,
                 fmaf(az, Wr[i].z, fmaf(aw, Wr[i].w, acc[r]))));
      }
    }
#pragma unroll
    for (int r = 0; r < 4; r++)
      if (r0 + r < N) h[(size_t)(r0 + r) * 64 + c] = acc[r];
  } else {  // DOUT == 16: lane owns (row r0 + lane/16, col lane%16)
    int myr = lane >> 4;
    float acc = 0.f;
#pragma unroll
    for (int i = 0; i < 16; i++) {
      int src = myr * 16 + i;
      float ax = __shfl(xv.x, src);
      float ay = __shfl(xv.y, src);
      float az = __shfl(xv.z, src);
      float aw = __shfl(xv.w, src);
      acc = fmaf(ax, Wr[i].x, fmaf(ay, Wr[i].y,
            fmaf(az, Wr[i].z, fmaf(aw, Wr[i].w, acc))));
    }
    if (r0 + myr < N) h[(size_t)(r0 + myr) * 16 + c] = acc;
  }
}

// Degree histograms over edges + self-loops (structure only, data-independent).
__global__ void hist_k(const int* __restrict__ ei, int* __restrict__ deg,
                       int* __restrict__ in_deg, int E, int N) {
  int e = blockIdx.x * blockDim.x + threadIdx.x;
  if (e >= E + N) return;
  int s, d;
  if (e < E) { s = ei[e]; d = ei[E + e]; }
  else       { s = e - E; d = s; }
  atomicAdd(deg + s, 1);
  atomicAdd(in_deg + d, 1);
}

// ---- 3-kernel exclusive scan over in_deg[N] (nbN <= 512) ----
__global__ void scan_reduce_k(const int* __restrict__ v, int* __restrict__ part, int n) {
  __shared__ int l[256];
  int i = blockIdx.x * 256 + threadIdx.x;
  l[threadIdx.x] = (i < n) ? v[i] : 0;
  __syncthreads();
  for (int o = 128; o > 0; o >>= 1) {
    if (threadIdx.x < o) l[threadIdx.x] += l[threadIdx.x + o];
    __syncthreads();
  }
  if (threadIdx.x == 0) part[blockIdx.x] = l[0];
}

__global__ void scan_part_k(int* __restrict__ part, int nb) {  // 1 block, 512 thr
  __shared__ int l[512];
  int t = threadIdx.x;
  int v = (t < nb) ? part[t] : 0;
  l[t] = v;
  __syncthreads();
  for (int o = 1; o < 512; o <<= 1) {
    int a = (t >= o) ? l[t - o] : 0;
    __syncthreads();
    l[t] += a;
    __syncthreads();
  }
  if (t < nb) part[t] = l[t] - v;  // exclusive
}

__global__ void scan_final_k(const int* __restrict__ v, const int* __restrict__ part,
                             int* __restrict__ off, int n) {
  __shared__ int l[256];
  int t = threadIdx.x;
  int i = blockIdx.x * 256 + t;
  int x = (i < n) ? v[i] : 0;
  l[t] = x;
  __syncthreads();
  for (int o = 1; o < 256; o <<= 1) {
    int a = (t >= o) ? l[t - o] : 0;
    __syncthreads();
    l[t] += a;
    __syncthreads();
  }
  if (i < n) off[i] = l[t] - x + part[blockIdx.x];
}

// Per edge: claim slot in dst's bucket, store src. Bucket order irrelevant.
__global__ void fill_struct_k(const int* __restrict__ ei, const int* __restrict__ off,
                              int* __restrict__ cnt, int* __restrict__ csr_src,
                              int E, int N) {
  int e = blockIdx.x * blockDim.x + threadIdx.x;
  if (e >= E + N) return;
  int s, d;
  if (e < E) { s = ei[e]; d = ei[E + e]; }
  else       { s = e - E; d = s; }
  csr_src[off[d] + atomicAdd(cnt + d, 1)] = s;
}

// Alpha pass over CSR: G=D/4 lanes per dst node; lane c holds h[dst] chunk c.
// Per in-edge: coalesced 256B (64B) read of h[src], dot via shfl_xor reduce,
// sign -> flag per CSR slot, histogram pos[src].
template <int D>
__global__ void alpha_csr_k(const int* __restrict__ csr_src, const int* __restrict__ off,
                            const int* __restrict__ indeg, const float* __restrict__ h,
                            unsigned char* __restrict__ flagb, int* __restrict__ pos, int N) {
  const int G = D / 4;
  int t = blockIdx.x * 256 + threadIdx.x;
  int node = t / G;
  int c = t & (G - 1);
  if (node >= N) return;
  const float4 hd = *(const float4*)(h + (size_t)node * D + c * 4);
  int j = off[node];
  int je = j + indeg[node];
  for (; j < je; ++j) {
    int s = csr_src[j];  // same addr across G lanes -> broadcast
    float4 hs = *(const float4*)(h + (size_t)s * D + c * 4);
    float p = fmaf(hs.x, hd.x, fmaf(hs.y, hd.y, fmaf(hs.z, hd.z, hs.w * hd.w)));
#pragma unroll
    for (int o = G / 2; o > 0; o >>= 1) p += __shfl_xor(p, o);
    if (c == 0) {
      bool pz = p > 0.f;
      flagb[j] = (unsigned char)pz;
      if (pz) atomicAdd(pos + s, 1);
    }
  }
}

__global__ void denom_k(const int* __restrict__ pos, const int* __restrict__ deg,
                        float* __restrict__ dinv, int N) {
  int i = blockIdx.x * blockDim.x + threadIdx.x;
  if (i >= N) return;
  int p = pos[i], dg = deg[i];
  dinv[i] = (p > 0) ? 1.f / ((float)p + (float)(dg - p) * EXPC)
                    : 1.f / (EXPC * (float)dg);
}

// Gather over CSR: G=D/4 lanes per node; acc starts at bias; one write per row.
// FUSE_LSM (D=16): 4-lane log-softmax in-register, writes final output.
template <int D, bool FUSE_LSM>
__global__ void gather_csr_k(const int* __restrict__ csr_src, const int* __restrict__ off,
                             const int* __restrict__ indeg,
                             const unsigned char* __restrict__ flagb,
                             const float* __restrict__ dinv, const float* __restrict__ h,
                             const float* __restrict__ b, float* __restrict__ outp, int N) {
  const int G = D / 4;
  int t = blockIdx.x * 256 + threadIdx.x;
  int node = t / G;
  int c = t & (G - 1);
  if (node >= N) return;
  float4 acc = *(const float4*)(b + c * 4);
  int j = off[node];
  int je = j + indeg[node];
  for (; j < je; ++j) {
    int s = csr_src[j];
    float w = (flagb[j] ? 1.f : EXPC) * dinv[s];
    float4 hv = *(const float4*)(h + (size_t)s * D + c * 4);
    acc.x = fmaf(w, hv.x, acc.x);
    acc.y = fmaf(w, hv.y, acc.y);
    acc.z = fmaf(w, hv.z, acc.z);
    acc.w = fmaf(w, hv.w, acc.w);
  }
  if (FUSE_LSM) {
    float m = fmaxf(fmaxf(acc.x, acc.y), fmaxf(acc.z, acc.w));
    m = fmaxf(m, __shfl_xor(m, 1));
    m = fmaxf(m, __shfl_xor(m, 2));
    float s = expf(acc.x - m) + expf(acc.y - m) + expf(acc.z - m) + expf(acc.w - m);
    s += __shfl_xor(s, 1);
    s += __shfl_xor(s, 2);
    float lse = m + logf(s);
    acc.x -= lse; acc.y -= lse; acc.z -= lse; acc.w -= lse;
  }
  *(float4*)(outp + (size_t)node * D + c * 4) = acc;
}

extern "C" void kernel_launch(void* const* d_in, const int* in_sizes, int n_in,
                              void* d_out, int out_size, void* d_ws, size_t ws_size,
                              hipStream_t stream) {
  const float* x = (const float*)d_in[0];
  const int* ei = (const int*)d_in[1];
  const float* W1 = (const float*)d_in[2];
  const float* b1 = (const float*)d_in[3];
  const float* W2 = (const float*)d_in[4];
  const float* b2 = (const float*)d_in[5];
  float* out = (float*)d_out;

  const int N = in_sizes[0] / 64;
  const int E = in_sizes[1] / 2;
  const int Et = E + N;
  const int B = 256;
  const int nbN = (N + B - 1) / B;  // 391 for N=100k; scan assumes <=512
  const int nbE = (Et + B - 1) / B;
  // gemm: one wave per 4 rows -> ceil(N/4) waves -> ceil(N/16) blocks of 256
  const int nbG = (N + 15) / 16;

  // Workspace (~63 MB).
  char* ws = (char*)d_ws;
  float* h1 = (float*)ws;      ws += (size_t)N * 64 * 4;  // 25.6 MB
  float* agg1 = (float*)ws;    ws += (size_t)N * 64 * 4;  // 25.6 MB
  int* deg = (int*)ws;         ws += (size_t)N * 4;       // [deg|in_deg|pos|cnt]
  int* in_deg = (int*)ws;      ws += (size_t)N * 4;
  int* pos = (int*)ws;         ws += (size_t)N * 4;
  int* cnt = (int*)ws;         ws += (size_t)N * 4;
  int* off = (int*)ws;         ws += (size_t)N * 4;
  float* dinv = (float*)ws;    ws += (size_t)N * 4;
  int* part = (int*)ws;        ws += 512 * 4;
  int* csr_src = (int*)ws;     ws += (size_t)Et * 4;      // 6.8 MB
  unsigned char* flagb = (unsigned char*)ws; ws += (size_t)Et;
  float* h2 = h1;  // alias: h1 dead once gather1 completes

  // ---- CSR structure (data-independent, built once) ----
  hipLaunchKernelGGL(zero_i32, dim3((4 * N + B - 1) / B), dim3(B), 0, stream, deg, 4 * N);
  hipLaunchKernelGGL(hist_k, dim3(nbE), dim3(B), 0, stream, ei, deg, in_deg, E, N);
  hipLaunchKernelGGL(scan_reduce_k, dim3(nbN), dim3(B), 0, stream, in_deg, part, N);
  hipLaunchKernelGGL(scan_part_k, dim3(1), dim3(512), 0, stream, part, nbN);
  hipLaunchKernelGGL(scan_final_k, dim3(nbN), dim3(B), 0, stream, in_deg, part, off, N);
  hipLaunchKernelGGL(fill_struct_k, dim3(nbE), dim3(B), 0, stream, ei, off, cnt, csr_src, E, N);

  // ---- layer 1 (D=64) ----
  hipLaunchKernelGGL((gemm_k<64, false>), dim3(nbG), dim3(B), 0, stream, x, W1, h1, N);
  hipLaunchKernelGGL((alpha_csr_k<64>), dim3(((size_t)N * 16 + B - 1) / B), dim3(B), 0,
                     stream, csr_src, off, in_deg, h1, flagb, pos, N);
  hipLaunchKernelGGL(denom_k, dim3(nbN), dim3(B), 0, stream, pos, deg, dinv, N);
  hipLaunchKernelGGL((gather_csr_k<64, false>), dim3(((size_t)N * 16 + B - 1) / B), dim3(B),
                     0, stream, csr_src, off, in_deg, flagb, dinv, h1, b1, agg1, N);

  // ---- layer 2 (D=16): relu folded into gemm load, log-softmax fused ----
  hipLaunchKernelGGL(zero_i32, dim3(nbN), dim3(B), 0, stream, pos, N);
  hipLaunchKernelGGL((gemm_k<16, true>), dim3(nbG), dim3(B), 0, stream, agg1, W2, h2, N);
  hipLaunchKernelGGL((alpha_csr_k<16>), dim3(((size_t)N * 4 + B - 1) / B), dim3(B), 0,
                     stream, csr_src, off, in_deg, h2, flagb, pos, N);
  hipLaunchKernelGGL(denom_k, dim3(nbN), dim3(B), 0, stream, pos, deg, dinv, N);
  hipLaunchKernelGGL((gather_csr_k<16, true>), dim3(((size_t)N * 4 + B - 1) / B), dim3(B),
                     0, stream, csr_src, off, in_deg, flagb, dinv, h2, b2, out, N);
}

// Round 6
// 1062.214 us; speedup vs baseline: 1.2006x; 1.2006x over previous
//
#include <hip/hip_runtime.h>

// GAT (2-layer) on MI355X — full-CSR formulation + LDS-tiled GEMMs.
// Closed-form segment softmax: alpha in {+t,-t}; per-src s: p=#pos out-edges,
// deg=out-degree (incl self-loop).
//   w = (flag?1:c) * dinv[s],  dinv = p>0 ? 1/(p+(deg-p)c) : 1/(c*deg).
// edge_index arrives as int32 (harness converts integer inputs).
// NOTE (R5 post-mortem): per-thread W register arrays (Wr[16] float4) spill
// to scratch (VGPR cap 64 -> 1.9 GB scratch traffic). Keep W in LDS.
#define EXPC 0.13533528323661270f  // exp(-2*1.0)

__global__ void zero_i32(int* __restrict__ p, int n) {
  int i = blockIdx.x * blockDim.x + threadIdx.x;
  if (i < n) p[i] = 0;
}

// h[N,64] = (RELU_IN ? relu(x) : x)[N,64] @ W[64,64]^T.
// 64-row tile per block, 256 threads as 16x16, 4x4 register blocking.
// All global loads/stores coalesced float4; x-tile + W^T staged in LDS.
template <bool RELU_IN>
__global__ void gemm64_k(const float* __restrict__ x, const float* __restrict__ W,
                         float* __restrict__ h, int N) {
  __shared__ float xs[64][68];   // row-major x tile, pad 68 (bank spread)
  __shared__ float wt[64][64];   // wt[k][c] = W[c][k]
  const int t = threadIdx.x;
  const int r0 = blockIdx.x * 64;
  for (int i = t; i < 4096; i += 256) {
    int c = i >> 6, k = i & 63;
    wt[k][c] = W[i];
  }
  for (int s = t; s < 1024; s += 256) {  // 64 rows x 16 float4
    int r = s >> 4, c4 = (s & 15) << 2;
    float4 v = make_float4(0.f, 0.f, 0.f, 0.f);
    if (r0 + r < N) {
      v = *(const float4*)(x + (size_t)(r0 + r) * 64 + c4);
      if (RELU_IN) {
        v.x = fmaxf(v.x, 0.f); v.y = fmaxf(v.y, 0.f);
        v.z = fmaxf(v.z, 0.f); v.w = fmaxf(v.w, 0.f);
      }
    }
    *(float4*)(&xs[r][c4]) = v;
  }
  __syncthreads();
  const int ty = t >> 4, tx = t & 15;  // rows 4ty.., cols 4tx..
  float acc[4][4] = {};
  for (int kk = 0; kk < 64; kk += 4) {
    float4 a[4], w[4];
#pragma unroll
    for (int i = 0; i < 4; i++) a[i] = *(const float4*)(&xs[4 * ty + i][kk]);
#pragma unroll
    for (int m = 0; m < 4; m++) w[m] = *(const float4*)(&wt[kk + m][4 * tx]);
#pragma unroll
    for (int i = 0; i < 4; i++) {
      acc[i][0] = fmaf(a[i].x, w[0].x, fmaf(a[i].y, w[1].x,
                  fmaf(a[i].z, w[2].x, fmaf(a[i].w, w[3].x, acc[i][0]))));
      acc[i][1] = fmaf(a[i].x, w[0].y, fmaf(a[i].y, w[1].y,
                  fmaf(a[i].z, w[2].y, fmaf(a[i].w, w[3].y, acc[i][1]))));
      acc[i][2] = fmaf(a[i].x, w[0].z, fmaf(a[i].y, w[1].z,
                  fmaf(a[i].z, w[2].z, fmaf(a[i].w, w[3].z, acc[i][2]))));
      acc[i][3] = fmaf(a[i].x, w[0].w, fmaf(a[i].y, w[1].w,
                  fmaf(a[i].z, w[2].w, fmaf(a[i].w, w[3].w, acc[i][3]))));
    }
  }
#pragma unroll
  for (int i = 0; i < 4; i++) {
    int row = r0 + 4 * ty + i;
    if (row < N)
      *(float4*)(h + (size_t)row * 64 + 4 * tx) =
          make_float4(acc[i][0], acc[i][1], acc[i][2], acc[i][3]);
  }
}

// h[N,16] = relu(x)[N,64] @ W[16,64]^T. 64-row tile; thread t -> (row t/4,
// float4 col group t%4). Coalesced loads/stores.
template <bool RELU_IN>
__global__ void gemm16_k(const float* __restrict__ x, const float* __restrict__ W,
                         float* __restrict__ h, int N) {
  __shared__ float xs[64][68];
  __shared__ float wt[64][16];  // wt[k][c] = W[c][k]
  const int t = threadIdx.x;
  const int r0 = blockIdx.x * 64;
  for (int i = t; i < 1024; i += 256) {
    int c = i >> 6, k = i & 63;
    wt[k][c] = W[i];
  }
  for (int s = t; s < 1024; s += 256) {
    int r = s >> 4, c4 = (s & 15) << 2;
    float4 v = make_float4(0.f, 0.f, 0.f, 0.f);
    if (r0 + r < N) {
      v = *(const float4*)(x + (size_t)(r0 + r) * 64 + c4);
      if (RELU_IN) {
        v.x = fmaxf(v.x, 0.f); v.y = fmaxf(v.y, 0.f);
        v.z = fmaxf(v.z, 0.f); v.w = fmaxf(v.w, 0.f);
      }
    }
    *(float4*)(&xs[r][c4]) = v;
  }
  __syncthreads();
  const int r = t >> 2, j = (t & 3) << 2;
  float4 acc = make_float4(0.f, 0.f, 0.f, 0.f);
  for (int k = 0; k < 64; k++) {
    float a = xs[r][k];
    float4 w = *(const float4*)(&wt[k][j]);
    acc.x = fmaf(a, w.x, acc.x);
    acc.y = fmaf(a, w.y, acc.y);
    acc.z = fmaf(a, w.z, acc.z);
    acc.w = fmaf(a, w.w, acc.w);
  }
  int row = r0 + r;
  if (row < N) *(float4*)(h + (size_t)row * 16 + j) = acc;
}

// Degree histograms over edges + self-loops (structure only, data-independent).
__global__ void hist_k(const int* __restrict__ ei, int* __restrict__ deg,
                       int* __restrict__ in_deg, int E, int N) {
  int e = blockIdx.x * blockDim.x + threadIdx.x;
  if (e >= E + N) return;
  int s, d;
  if (e < E) { s = ei[e]; d = ei[E + e]; }
  else       { s = e - E; d = s; }
  atomicAdd(deg + s, 1);
  atomicAdd(in_deg + d, 1);
}

// ---- 3-kernel exclusive scan over in_deg[N] (nbN <= 512) ----
__global__ void scan_reduce_k(const int* __restrict__ v, int* __restrict__ part, int n) {
  __shared__ int l[256];
  int i = blockIdx.x * 256 + threadIdx.x;
  l[threadIdx.x] = (i < n) ? v[i] : 0;
  __syncthreads();
  for (int o = 128; o > 0; o >>= 1) {
    if (threadIdx.x < o) l[threadIdx.x] += l[threadIdx.x + o];
    __syncthreads();
  }
  if (threadIdx.x == 0) part[blockIdx.x] = l[0];
}

__global__ void scan_part_k(int* __restrict__ part, int nb) {  // 1 block, 512 thr
  __shared__ int l[512];
  int t = threadIdx.x;
  int v = (t < nb) ? part[t] : 0;
  l[t] = v;
  __syncthreads();
  for (int o = 1; o < 512; o <<= 1) {
    int a = (t >= o) ? l[t - o] : 0;
    __syncthreads();
    l[t] += a;
    __syncthreads();
  }
  if (t < nb) part[t] = l[t] - v;  // exclusive
}

__global__ void scan_final_k(const int* __restrict__ v, const int* __restrict__ part,
                             int* __restrict__ off, int n) {
  __shared__ int l[256];
  int t = threadIdx.x;
  int i = blockIdx.x * 256 + t;
  int x = (i < n) ? v[i] : 0;
  l[t] = x;
  __syncthreads();
  for (int o = 1; o < 256; o <<= 1) {
    int a = (t >= o) ? l[t - o] : 0;
    __syncthreads();
    l[t] += a;
    __syncthreads();
  }
  if (i < n) off[i] = l[t] - x + part[blockIdx.x];
}

// Per edge: claim slot in dst's bucket, store src. Bucket order irrelevant.
__global__ void fill_struct_k(const int* __restrict__ ei, const int* __restrict__ off,
                              int* __restrict__ cnt, int* __restrict__ csr_src,
                              int E, int N) {
  int e = blockIdx.x * blockDim.x + threadIdx.x;
  if (e >= E + N) return;
  int s, d;
  if (e < E) { s = ei[e]; d = ei[E + e]; }
  else       { s = e - E; d = s; }
  csr_src[off[d] + atomicAdd(cnt + d, 1)] = s;
}

// Alpha pass over CSR: G=D/4 lanes per dst node; lane c holds h[dst] chunk c.
template <int D>
__global__ void alpha_csr_k(const int* __restrict__ csr_src, const int* __restrict__ off,
                            const int* __restrict__ indeg, const float* __restrict__ h,
                            unsigned char* __restrict__ flagb, int* __restrict__ pos, int N) {
  const int G = D / 4;
  int t = blockIdx.x * 256 + threadIdx.x;
  int node = t / G;
  int c = t & (G - 1);
  if (node >= N) return;
  const float4 hd = *(const float4*)(h + (size_t)node * D + c * 4);
  int j = off[node];
  int je = j + indeg[node];
  for (; j < je; ++j) {
    int s = csr_src[j];  // same addr across G lanes -> broadcast
    float4 hs = *(const float4*)(h + (size_t)s * D + c * 4);
    float p = fmaf(hs.x, hd.x, fmaf(hs.y, hd.y, fmaf(hs.z, hd.z, hs.w * hd.w)));
#pragma unroll
    for (int o = G / 2; o > 0; o >>= 1) p += __shfl_xor(p, o);
    if (c == 0) {
      bool pz = p > 0.f;
      flagb[j] = (unsigned char)pz;
      if (pz) atomicAdd(pos + s, 1);
    }
  }
}

__global__ void denom_k(const int* __restrict__ pos, const int* __restrict__ deg,
                        float* __restrict__ dinv, int N) {
  int i = blockIdx.x * blockDim.x + threadIdx.x;
  if (i >= N) return;
  int p = pos[i], dg = deg[i];
  dinv[i] = (p > 0) ? 1.f / ((float)p + (float)(dg - p) * EXPC)
                    : 1.f / (EXPC * (float)dg);
}

// Gather over CSR: G=D/4 lanes per node; acc starts at bias; one write per row.
// FUSE_LSM (D=16): 4-lane log-softmax in-register, writes final output.
template <int D, bool FUSE_LSM>
__global__ void gather_csr_k(const int* __restrict__ csr_src, const int* __restrict__ off,
                             const int* __restrict__ indeg,
                             const unsigned char* __restrict__ flagb,
                             const float* __restrict__ dinv, const float* __restrict__ h,
                             const float* __restrict__ b, float* __restrict__ outp, int N) {
  const int G = D / 4;
  int t = blockIdx.x * 256 + threadIdx.x;
  int node = t / G;
  int c = t & (G - 1);
  if (node >= N) return;
  float4 acc = *(const float4*)(b + c * 4);
  int j = off[node];
  int je = j + indeg[node];
  for (; j < je; ++j) {
    int s = csr_src[j];
    float w = (flagb[j] ? 1.f : EXPC) * dinv[s];
    float4 hv = *(const float4*)(h + (size_t)s * D + c * 4);
    acc.x = fmaf(w, hv.x, acc.x);
    acc.y = fmaf(w, hv.y, acc.y);
    acc.z = fmaf(w, hv.z, acc.z);
    acc.w = fmaf(w, hv.w, acc.w);
  }
  if (FUSE_LSM) {
    float m = fmaxf(fmaxf(acc.x, acc.y), fmaxf(acc.z, acc.w));
    m = fmaxf(m, __shfl_xor(m, 1));
    m = fmaxf(m, __shfl_xor(m, 2));
    float s = expf(acc.x - m) + expf(acc.y - m) + expf(acc.z - m) + expf(acc.w - m);
    s += __shfl_xor(s, 1);
    s += __shfl_xor(s, 2);
    float lse = m + logf(s);
    acc.x -= lse; acc.y -= lse; acc.z -= lse; acc.w -= lse;
  }
  *(float4*)(outp + (size_t)node * D + c * 4) = acc;
}

extern "C" void kernel_launch(void* const* d_in, const int* in_sizes, int n_in,
                              void* d_out, int out_size, void* d_ws, size_t ws_size,
                              hipStream_t stream) {
  const float* x = (const float*)d_in[0];
  const int* ei = (const int*)d_in[1];
  const float* W1 = (const float*)d_in[2];
  const float* b1 = (const float*)d_in[3];
  const float* W2 = (const float*)d_in[4];
  const float* b2 = (const float*)d_in[5];
  float* out = (float*)d_out;

  const int N = in_sizes[0] / 64;
  const int E = in_sizes[1] / 2;
  const int Et = E + N;
  const int B = 256;
  const int nbN = (N + B - 1) / B;  // 391 for N=100k; scan assumes <=512
  const int nbE = (Et + B - 1) / B;
  const int nbT = (N + 63) / 64;    // 64-row GEMM tiles

  // Workspace (~63 MB).
  char* ws = (char*)d_ws;
  float* h1 = (float*)ws;      ws += (size_t)N * 64 * 4;  // 25.6 MB
  float* agg1 = (float*)ws;    ws += (size_t)N * 64 * 4;  // 25.6 MB
  int* deg = (int*)ws;         ws += (size_t)N * 4;       // [deg|in_deg|pos|cnt]
  int* in_deg = (int*)ws;      ws += (size_t)N * 4;
  int* pos = (int*)ws;         ws += (size_t)N * 4;
  int* cnt = (int*)ws;         ws += (size_t)N * 4;
  int* off = (int*)ws;         ws += (size_t)N * 4;
  float* dinv = (float*)ws;    ws += (size_t)N * 4;
  int* part = (int*)ws;        ws += 512 * 4;
  int* csr_src = (int*)ws;     ws += (size_t)Et * 4;      // 6.8 MB
  unsigned char* flagb = (unsigned char*)ws; ws += (size_t)Et;
  float* h2 = h1;  // alias: h1 dead once gather1 completes

  // ---- CSR structure (data-independent, built once) ----
  hipLaunchKernelGGL(zero_i32, dim3((4 * N + B - 1) / B), dim3(B), 0, stream, deg, 4 * N);
  hipLaunchKernelGGL(hist_k, dim3(nbE), dim3(B), 0, stream, ei, deg, in_deg, E, N);
  hipLaunchKernelGGL(scan_reduce_k, dim3(nbN), dim3(B), 0, stream, in_deg, part, N);
  hipLaunchKernelGGL(scan_part_k, dim3(1), dim3(512), 0, stream, part, nbN);
  hipLaunchKernelGGL(scan_final_k, dim3(nbN), dim3(B), 0, stream, in_deg, part, off, N);
  hipLaunchKernelGGL(fill_struct_k, dim3(nbE), dim3(B), 0, stream, ei, off, cnt, csr_src, E, N);

  // ---- layer 1 (D=64) ----
  hipLaunchKernelGGL((gemm64_k<false>), dim3(nbT), dim3(B), 0, stream, x, W1, h1, N);
  hipLaunchKernelGGL((alpha_csr_k<64>), dim3(((size_t)N * 16 + B - 1) / B), dim3(B), 0,
                     stream, csr_src, off, in_deg, h1, flagb, pos, N);
  hipLaunchKernelGGL(denom_k, dim3(nbN), dim3(B), 0, stream, pos, deg, dinv, N);
  hipLaunchKernelGGL((gather_csr_k<64, false>), dim3(((size_t)N * 16 + B - 1) / B), dim3(B),
                     0, stream, csr_src, off, in_deg, flagb, dinv, h1, b1, agg1, N);

  // ---- layer 2 (D=16): relu folded into gemm load, log-softmax fused ----
  hipLaunchKernelGGL(zero_i32, dim3(nbN), dim3(B), 0, stream, pos, N);
  hipLaunchKernelGGL((gemm16_k<true>), dim3(nbT), dim3(B), 0, stream, agg1, W2, h2, N);
  hipLaunchKernelGGL((alpha_csr_k<16>), dim3(((size_t)N * 4 + B - 1) / B), dim3(B), 0,
                     stream, csr_src, off, in_deg, h2, flagb, pos, N);
  hipLaunchKernelGGL(denom_k, dim3(nbN), dim3(B), 0, stream, pos, deg, dinv, N);
  hipLaunchKernelGGL((gather_csr_k<16, true>), dim3(((size_t)N * 4 + B - 1) / B), dim3(B),
                     0, stream, csr_src, off, in_deg, flagb, dinv, h2, b2, out, N);
}

// Round 7
// 835.230 us; speedup vs baseline: 1.5268x; 1.2718x over previous
//
#include <hip/hip_runtime.h>

// GAT (2-layer) on MI355X — full-CSR formulation + LDS-tiled GEMMs.
// Closed-form segment softmax: alpha in {+t,-t}; per-src s: p=#pos out-edges,
// deg=out-degree (incl self-loop).
//   w = (flag?1:c) * dinv[s],  dinv = p>0 ? 1/(p+(deg-p)c) : 1/(c*deg).
// edge_index arrives as int32 (harness converts integer inputs).
// R5 post-mortem: per-thread W register arrays spill -> keep W in LDS.
// R6 post-mortem: no __launch_bounds__ -> VGPR cap 64 -> a[]/w[] spill ->
//   1.4 GB scratch traffic. Also wt[64][64] staging = 64-way bank conflict.
#define EXPC 0.13533528323661270f  // exp(-2*1.0)

__global__ void zero_i32(int* __restrict__ p, int n) {
  int i = blockIdx.x * blockDim.x + threadIdx.x;
  if (i < n) p[i] = 0;
}

// h[N,64] = (RELU_IN ? relu(x) : x)[N,64] @ W[64,64]^T.
// 64-row tile per block, 256 threads as 16x16, 4x4 register blocking.
// launch_bounds(256,2): VGPR cap 256 -> no spill (~70 live).
template <bool RELU_IN>
__global__ void __launch_bounds__(256, 2)
gemm64_k(const float* __restrict__ x, const float* __restrict__ W,
         float* __restrict__ h, int N) {
  __shared__ float xs[64][68];   // pad 68: staging + reads conflict-lite
  __shared__ float wt[64][68];   // wt[k][c] = W[c][k]; pad 68: 8-way not 64-way
  const int t = threadIdx.x;
  const int r0 = blockIdx.x * 64;
  for (int i = t; i < 4096; i += 256) {
    int c = i >> 6, k = i & 63;
    wt[k][c] = W[i];
  }
  for (int s = t; s < 1024; s += 256) {  // 64 rows x 16 float4
    int r = s >> 4, c4 = (s & 15) << 2;
    float4 v = make_float4(0.f, 0.f, 0.f, 0.f);
    if (r0 + r < N) {
      v = *(const float4*)(x + (size_t)(r0 + r) * 64 + c4);
      if (RELU_IN) {
        v.x = fmaxf(v.x, 0.f); v.y = fmaxf(v.y, 0.f);
        v.z = fmaxf(v.z, 0.f); v.w = fmaxf(v.w, 0.f);
      }
    }
    *(float4*)(&xs[r][c4]) = v;
  }
  __syncthreads();
  const int ty = t >> 4, tx = t & 15;  // rows 4ty.., cols 4tx..
  float acc[4][4] = {};
  for (int kk = 0; kk < 64; kk += 4) {
    float4 a[4], w[4];
#pragma unroll
    for (int i = 0; i < 4; i++) a[i] = *(const float4*)(&xs[4 * ty + i][kk]);
#pragma unroll
    for (int m = 0; m < 4; m++) w[m] = *(const float4*)(&wt[kk + m][4 * tx]);
#pragma unroll
    for (int i = 0; i < 4; i++) {
      acc[i][0] = fmaf(a[i].x, w[0].x, fmaf(a[i].y, w[1].x,
                  fmaf(a[i].z, w[2].x, fmaf(a[i].w, w[3].x, acc[i][0]))));
      acc[i][1] = fmaf(a[i].x, w[0].y, fmaf(a[i].y, w[1].y,
                  fmaf(a[i].z, w[2].y, fmaf(a[i].w, w[3].y, acc[i][1]))));
      acc[i][2] = fmaf(a[i].x, w[0].z, fmaf(a[i].y, w[1].z,
                  fmaf(a[i].z, w[2].z, fmaf(a[i].w, w[3].z, acc[i][2]))));
      acc[i][3] = fmaf(a[i].x, w[0].w, fmaf(a[i].y, w[1].w,
                  fmaf(a[i].z, w[2].w, fmaf(a[i].w, w[3].w, acc[i][3]))));
    }
  }
#pragma unroll
  for (int i = 0; i < 4; i++) {
    int row = r0 + 4 * ty + i;
    if (row < N)
      *(float4*)(h + (size_t)row * 64 + 4 * tx) =
          make_float4(acc[i][0], acc[i][1], acc[i][2], acc[i][3]);
  }
}

// h[N,16] = relu(x)[N,64] @ W[16,64]^T. 64-row tile; thread t -> (row t/4,
// float4 col group t%4). wt pad 20: 8-way staging, aligned cf float4 reads.
template <bool RELU_IN>
__global__ void __launch_bounds__(256, 2)
gemm16_k(const float* __restrict__ x, const float* __restrict__ W,
         float* __restrict__ h, int N) {
  __shared__ float xs[64][68];
  __shared__ float wt[64][20];  // wt[k][c] = W[c][k]
  const int t = threadIdx.x;
  const int r0 = blockIdx.x * 64;
  for (int i = t; i < 1024; i += 256) {
    int c = i >> 6, k = i & 63;
    wt[k][c] = W[i];
  }
  for (int s = t; s < 1024; s += 256) {
    int r = s >> 4, c4 = (s & 15) << 2;
    float4 v = make_float4(0.f, 0.f, 0.f, 0.f);
    if (r0 + r < N) {
      v = *(const float4*)(x + (size_t)(r0 + r) * 64 + c4);
      if (RELU_IN) {
        v.x = fmaxf(v.x, 0.f); v.y = fmaxf(v.y, 0.f);
        v.z = fmaxf(v.z, 0.f); v.w = fmaxf(v.w, 0.f);
      }
    }
    *(float4*)(&xs[r][c4]) = v;
  }
  __syncthreads();
  const int r = t >> 2, j = (t & 3) << 2;
  float4 acc = make_float4(0.f, 0.f, 0.f, 0.f);
  for (int k = 0; k < 64; k++) {
    float a = xs[r][k];
    float4 w = *(const float4*)(&wt[k][j]);
    acc.x = fmaf(a, w.x, acc.x);
    acc.y = fmaf(a, w.y, acc.y);
    acc.z = fmaf(a, w.z, acc.z);
    acc.w = fmaf(a, w.w, acc.w);
  }
  int row = r0 + r;
  if (row < N) *(float4*)(h + (size_t)row * 16 + j) = acc;
}

// Degree histograms over edges + self-loops (structure only, data-independent).
__global__ void hist_k(const int* __restrict__ ei, int* __restrict__ deg,
                       int* __restrict__ in_deg, int E, int N) {
  int e = blockIdx.x * blockDim.x + threadIdx.x;
  if (e >= E + N) return;
  int s, d;
  if (e < E) { s = ei[e]; d = ei[E + e]; }
  else       { s = e - E; d = s; }
  atomicAdd(deg + s, 1);
  atomicAdd(in_deg + d, 1);
}

// ---- 3-kernel exclusive scan over in_deg[N] (nbN <= 512) ----
__global__ void scan_reduce_k(const int* __restrict__ v, int* __restrict__ part, int n) {
  __shared__ int l[256];
  int i = blockIdx.x * 256 + threadIdx.x;
  l[threadIdx.x] = (i < n) ? v[i] : 0;
  __syncthreads();
  for (int o = 128; o > 0; o >>= 1) {
    if (threadIdx.x < o) l[threadIdx.x] += l[threadIdx.x + o];
    __syncthreads();
  }
  if (threadIdx.x == 0) part[blockIdx.x] = l[0];
}

__global__ void scan_part_k(int* __restrict__ part, int nb) {  // 1 block, 512 thr
  __shared__ int l[512];
  int t = threadIdx.x;
  int v = (t < nb) ? part[t] : 0;
  l[t] = v;
  __syncthreads();
  for (int o = 1; o < 512; o <<= 1) {
    int a = (t >= o) ? l[t - o] : 0;
    __syncthreads();
    l[t] += a;
    __syncthreads();
  }
  if (t < nb) part[t] = l[t] - v;  // exclusive
}

__global__ void scan_final_k(const int* __restrict__ v, const int* __restrict__ part,
                             int* __restrict__ off, int n) {
  __shared__ int l[256];
  int t = threadIdx.x;
  int i = blockIdx.x * 256 + t;
  int x = (i < n) ? v[i] : 0;
  l[t] = x;
  __syncthreads();
  for (int o = 1; o < 256; o <<= 1) {
    int a = (t >= o) ? l[t - o] : 0;
    __syncthreads();
    l[t] += a;
    __syncthreads();
  }
  if (i < n) off[i] = l[t] - x + part[blockIdx.x];
}

// Per edge: claim slot in dst's bucket, store src. Bucket order irrelevant.
__global__ void fill_struct_k(const int* __restrict__ ei, const int* __restrict__ off,
                              int* __restrict__ cnt, int* __restrict__ csr_src,
                              int E, int N) {
  int e = blockIdx.x * blockDim.x + threadIdx.x;
  if (e >= E + N) return;
  int s, d;
  if (e < E) { s = ei[e]; d = ei[E + e]; }
  else       { s = e - E; d = s; }
  csr_src[off[d] + atomicAdd(cnt + d, 1)] = s;
}

// Alpha pass over CSR: G=D/4 lanes per dst node; lane c holds h[dst] chunk c.
template <int D>
__global__ void alpha_csr_k(const int* __restrict__ csr_src, const int* __restrict__ off,
                            const int* __restrict__ indeg, const float* __restrict__ h,
                            unsigned char* __restrict__ flagb, int* __restrict__ pos, int N) {
  const int G = D / 4;
  int t = blockIdx.x * 256 + threadIdx.x;
  int node = t / G;
  int c = t & (G - 1);
  if (node >= N) return;
  const float4 hd = *(const float4*)(h + (size_t)node * D + c * 4);
  int j = off[node];
  int je = j + indeg[node];
  for (; j < je; ++j) {
    int s = csr_src[j];  // same addr across G lanes -> broadcast
    float4 hs = *(const float4*)(h + (size_t)s * D + c * 4);
    float p = fmaf(hs.x, hd.x, fmaf(hs.y, hd.y, fmaf(hs.z, hd.z, hs.w * hd.w)));
#pragma unroll
    for (int o = G / 2; o > 0; o >>= 1) p += __shfl_xor(p, o);
    if (c == 0) {
      bool pz = p > 0.f;
      flagb[j] = (unsigned char)pz;
      if (pz) atomicAdd(pos + s, 1);
    }
  }
}

__global__ void denom_k(const int* __restrict__ pos, const int* __restrict__ deg,
                        float* __restrict__ dinv, int N) {
  int i = blockIdx.x * blockDim.x + threadIdx.x;
  if (i >= N) return;
  int p = pos[i], dg = deg[i];
  dinv[i] = (p > 0) ? 1.f / ((float)p + (float)(dg - p) * EXPC)
                    : 1.f / (EXPC * (float)dg);
}

// Gather over CSR: G=D/4 lanes per node; acc starts at bias; one write per row.
// FUSE_LSM (D=16): 4-lane log-softmax in-register, writes final output.
template <int D, bool FUSE_LSM>
__global__ void gather_csr_k(const int* __restrict__ csr_src, const int* __restrict__ off,
                             const int* __restrict__ indeg,
                             const unsigned char* __restrict__ flagb,
                             const float* __restrict__ dinv, const float* __restrict__ h,
                             const float* __restrict__ b, float* __restrict__ outp, int N) {
  const int G = D / 4;
  int t = blockIdx.x * 256 + threadIdx.x;
  int node = t / G;
  int c = t & (G - 1);
  if (node >= N) return;
  float4 acc = *(const float4*)(b + c * 4);
  int j = off[node];
  int je = j + indeg[node];
  for (; j < je; ++j) {
    int s = csr_src[j];
    float w = (flagb[j] ? 1.f : EXPC) * dinv[s];
    float4 hv = *(const float4*)(h + (size_t)s * D + c * 4);
    acc.x = fmaf(w, hv.x, acc.x);
    acc.y = fmaf(w, hv.y, acc.y);
    acc.z = fmaf(w, hv.z, acc.z);
    acc.w = fmaf(w, hv.w, acc.w);
  }
  if (FUSE_LSM) {
    float m = fmaxf(fmaxf(acc.x, acc.y), fmaxf(acc.z, acc.w));
    m = fmaxf(m, __shfl_xor(m, 1));
    m = fmaxf(m, __shfl_xor(m, 2));
    float s = expf(acc.x - m) + expf(acc.y - m) + expf(acc.z - m) + expf(acc.w - m);
    s += __shfl_xor(s, 1);
    s += __shfl_xor(s, 2);
    float lse = m + logf(s);
    acc.x -= lse; acc.y -= lse; acc.z -= lse; acc.w -= lse;
  }
  *(float4*)(outp + (size_t)node * D + c * 4) = acc;
}

extern "C" void kernel_launch(void* const* d_in, const int* in_sizes, int n_in,
                              void* d_out, int out_size, void* d_ws, size_t ws_size,
                              hipStream_t stream) {
  const float* x = (const float*)d_in[0];
  const int* ei = (const int*)d_in[1];
  const float* W1 = (const float*)d_in[2];
  const float* b1 = (const float*)d_in[3];
  const float* W2 = (const float*)d_in[4];
  const float* b2 = (const float*)d_in[5];
  float* out = (float*)d_out;

  const int N = in_sizes[0] / 64;
  const int E = in_sizes[1] / 2;
  const int Et = E + N;
  const int B = 256;
  const int nbN = (N + B - 1) / B;  // 391 for N=100k; scan assumes <=512
  const int nbE = (Et + B - 1) / B;
  const int nbT = (N + 63) / 64;    // 64-row GEMM tiles

  // Workspace (~63 MB).
  char* ws = (char*)d_ws;
  float* h1 = (float*)ws;      ws += (size_t)N * 64 * 4;  // 25.6 MB
  float* agg1 = (float*)ws;    ws += (size_t)N * 64 * 4;  // 25.6 MB
  int* deg = (int*)ws;         ws += (size_t)N * 4;       // [deg|in_deg|pos|cnt]
  int* in_deg = (int*)ws;      ws += (size_t)N * 4;
  int* pos = (int*)ws;         ws += (size_t)N * 4;
  int* cnt = (int*)ws;         ws += (size_t)N * 4;
  int* off = (int*)ws;         ws += (size_t)N * 4;
  float* dinv = (float*)ws;    ws += (size_t)N * 4;
  int* part = (int*)ws;        ws += 512 * 4;
  int* csr_src = (int*)ws;     ws += (size_t)Et * 4;      // 6.8 MB
  unsigned char* flagb = (unsigned char*)ws; ws += (size_t)Et;
  float* h2 = h1;  // alias: h1 dead once gather1 completes

  // ---- CSR structure (data-independent, built once) ----
  hipLaunchKernelGGL(zero_i32, dim3((4 * N + B - 1) / B), dim3(B), 0, stream, deg, 4 * N);
  hipLaunchKernelGGL(hist_k, dim3(nbE), dim3(B), 0, stream, ei, deg, in_deg, E, N);
  hipLaunchKernelGGL(scan_reduce_k, dim3(nbN), dim3(B), 0, stream, in_deg, part, N);
  hipLaunchKernelGGL(scan_part_k, dim3(1), dim3(512), 0, stream, part, nbN);
  hipLaunchKernelGGL(scan_final_k, dim3(nbN), dim3(B), 0, stream, in_deg, part, off, N);
  hipLaunchKernelGGL(fill_struct_k, dim3(nbE), dim3(B), 0, stream, ei, off, cnt, csr_src, E, N);

  // ---- layer 1 (D=64) ----
  hipLaunchKernelGGL((gemm64_k<false>), dim3(nbT), dim3(B), 0, stream, x, W1, h1, N);
  hipLaunchKernelGGL((alpha_csr_k<64>), dim3(((size_t)N * 16 + B - 1) / B), dim3(B), 0,
                     stream, csr_src, off, in_deg, h1, flagb, pos, N);
  hipLaunchKernelGGL(denom_k, dim3(nbN), dim3(B), 0, stream, pos, deg, dinv, N);
  hipLaunchKernelGGL((gather_csr_k<64, false>), dim3(((size_t)N * 16 + B - 1) / B), dim3(B),
                     0, stream, csr_src, off, in_deg, flagb, dinv, h1, b1, agg1, N);

  // ---- layer 2 (D=16): relu folded into gemm load, log-softmax fused ----
  hipLaunchKernelGGL(zero_i32, dim3(nbN), dim3(B), 0, stream, pos, N);
  hipLaunchKernelGGL((gemm16_k<true>), dim3(nbT), dim3(B), 0, stream, agg1, W2, h2, N);
  hipLaunchKernelGGL((alpha_csr_k<16>), dim3(((size_t)N * 4 + B - 1) / B), dim3(B), 0,
                     stream, csr_src, off, in_deg, h2, flagb, pos, N);
  hipLaunchKernelGGL(denom_k, dim3(nbN), dim3(B), 0, stream, pos, deg, dinv, N);
  hipLaunchKernelGGL((gather_csr_k<16, true>), dim3(((size_t)N * 4 + B - 1) / B), dim3(B),
                     0, stream, csr_src, off, in_deg, flagb, dinv, h2, b2, out, N);
}

// Round 8
// 632.312 us; speedup vs baseline: 2.0168x; 1.3209x over previous
//
#include <hip/hip_runtime.h>

// GAT (2-layer) on MI355X — full-CSR formulation + LDS-tiled GEMMs.
// Closed-form segment softmax: alpha in {+t,-t}; per-src s: p=#pos out-edges,
// deg=out-degree (incl self-loop).
//   w = (flag?1:c) * dinv[s],  dinv = p>0 ? 1/(p+(deg-p)c) : 1/(c*deg).
// edge_index arrives as int32 (harness converts integer inputs).
// R5: per-thread W register arrays spill -> keep W in LDS.
// R6: no __launch_bounds__ -> VGPR cap 64 -> spill (1.4 GB scratch).
//     wt[64][64] staging = 64-way bank conflict -> pad to [68].
// R7: __launch_bounds__(256,2) -> allocator still capped at 128, partial
//     spill remains (0.8 GB scratch). -> (256,1): cap 512, no spill.
#define EXPC 0.13533528323661270f  // exp(-2*1.0)

__global__ void zero_i32(int* __restrict__ p, int n) {
  int i = blockIdx.x * blockDim.x + threadIdx.x;
  if (i < n) p[i] = 0;
}

// h[N,64] = (RELU_IN ? relu(x) : x)[N,64] @ W[64,64]^T.
// 64-row tile per block, 256 threads as 16x16, 4x4 register blocking.
// launch_bounds(256,1): let the allocator use what it needs (~70 live).
template <bool RELU_IN>
__global__ void __launch_bounds__(256, 1)
gemm64_k(const float* __restrict__ x, const float* __restrict__ W,
         float* __restrict__ h, int N) {
  __shared__ float xs[64][68];   // pad 68: staging + reads conflict-lite
  __shared__ float wt[64][68];   // wt[k][c] = W[c][k]; pad 68: 8-way not 64-way
  const int t = threadIdx.x;
  const int r0 = blockIdx.x * 64;
  for (int i = t; i < 4096; i += 256) {
    int c = i >> 6, k = i & 63;
    wt[k][c] = W[i];
  }
  for (int s = t; s < 1024; s += 256) {  // 64 rows x 16 float4
    int r = s >> 4, c4 = (s & 15) << 2;
    float4 v = make_float4(0.f, 0.f, 0.f, 0.f);
    if (r0 + r < N) {
      v = *(const float4*)(x + (size_t)(r0 + r) * 64 + c4);
      if (RELU_IN) {
        v.x = fmaxf(v.x, 0.f); v.y = fmaxf(v.y, 0.f);
        v.z = fmaxf(v.z, 0.f); v.w = fmaxf(v.w, 0.f);
      }
    }
    *(float4*)(&xs[r][c4]) = v;
  }
  __syncthreads();
  const int ty = t >> 4, tx = t & 15;  // rows 4ty.., cols 4tx..
  float acc[4][4] = {};
  for (int kk = 0; kk < 64; kk += 4) {
    float4 a[4], w[4];
#pragma unroll
    for (int i = 0; i < 4; i++) a[i] = *(const float4*)(&xs[4 * ty + i][kk]);
#pragma unroll
    for (int m = 0; m < 4; m++) w[m] = *(const float4*)(&wt[kk + m][4 * tx]);
#pragma unroll
    for (int i = 0; i < 4; i++) {
      acc[i][0] = fmaf(a[i].x, w[0].x, fmaf(a[i].y, w[1].x,
                  fmaf(a[i].z, w[2].x, fmaf(a[i].w, w[3].x, acc[i][0]))));
      acc[i][1] = fmaf(a[i].x, w[0].y, fmaf(a[i].y, w[1].y,
                  fmaf(a[i].z, w[2].y, fmaf(a[i].w, w[3].y, acc[i][1]))));
      acc[i][2] = fmaf(a[i].x, w[0].z, fmaf(a[i].y, w[1].z,
                  fmaf(a[i].z, w[2].z, fmaf(a[i].w, w[3].z, acc[i][2]))));
      acc[i][3] = fmaf(a[i].x, w[0].w, fmaf(a[i].y, w[1].w,
                  fmaf(a[i].z, w[2].w, fmaf(a[i].w, w[3].w, acc[i][3]))));
    }
  }
#pragma unroll
  for (int i = 0; i < 4; i++) {
    int row = r0 + 4 * ty + i;
    if (row < N)
      *(float4*)(h + (size_t)row * 64 + 4 * tx) =
          make_float4(acc[i][0], acc[i][1], acc[i][2], acc[i][3]);
  }
}

// h[N,16] = relu(x)[N,64] @ W[16,64]^T. 64-row tile; thread t -> (row t/4,
// float4 col group t%4). wt pad 20: 8-way staging, aligned cf float4 reads.
template <bool RELU_IN>
__global__ void __launch_bounds__(256, 2)
gemm16_k(const float* __restrict__ x, const float* __restrict__ W,
         float* __restrict__ h, int N) {
  __shared__ float xs[64][68];
  __shared__ float wt[64][20];  // wt[k][c] = W[c][k]
  const int t = threadIdx.x;
  const int r0 = blockIdx.x * 64;
  for (int i = t; i < 1024; i += 256) {
    int c = i >> 6, k = i & 63;
    wt[k][c] = W[i];
  }
  for (int s = t; s < 1024; s += 256) {
    int r = s >> 4, c4 = (s & 15) << 2;
    float4 v = make_float4(0.f, 0.f, 0.f, 0.f);
    if (r0 + r < N) {
      v = *(const float4*)(x + (size_t)(r0 + r) * 64 + c4);
      if (RELU_IN) {
        v.x = fmaxf(v.x, 0.f); v.y = fmaxf(v.y, 0.f);
        v.z = fmaxf(v.z, 0.f); v.w = fmaxf(v.w, 0.f);
      }
    }
    *(float4*)(&xs[r][c4]) = v;
  }
  __syncthreads();
  const int r = t >> 2, j = (t & 3) << 2;
  float4 acc = make_float4(0.f, 0.f, 0.f, 0.f);
  for (int k = 0; k < 64; k++) {
    float a = xs[r][k];
    float4 w = *(const float4*)(&wt[k][j]);
    acc.x = fmaf(a, w.x, acc.x);
    acc.y = fmaf(a, w.y, acc.y);
    acc.z = fmaf(a, w.z, acc.z);
    acc.w = fmaf(a, w.w, acc.w);
  }
  int row = r0 + r;
  if (row < N) *(float4*)(h + (size_t)row * 16 + j) = acc;
}

// Degree histograms over edges + self-loops (structure only, data-independent).
__global__ void hist_k(const int* __restrict__ ei, int* __restrict__ deg,
                       int* __restrict__ in_deg, int E, int N) {
  int e = blockIdx.x * blockDim.x + threadIdx.x;
  if (e >= E + N) return;
  int s, d;
  if (e < E) { s = ei[e]; d = ei[E + e]; }
  else       { s = e - E; d = s; }
  atomicAdd(deg + s, 1);
  atomicAdd(in_deg + d, 1);
}

// ---- 3-kernel exclusive scan over in_deg[N] (nbN <= 512) ----
__global__ void scan_reduce_k(const int* __restrict__ v, int* __restrict__ part, int n) {
  __shared__ int l[256];
  int i = blockIdx.x * 256 + threadIdx.x;
  l[threadIdx.x] = (i < n) ? v[i] : 0;
  __syncthreads();
  for (int o = 128; o > 0; o >>= 1) {
    if (threadIdx.x < o) l[threadIdx.x] += l[threadIdx.x + o];
    __syncthreads();
  }
  if (threadIdx.x == 0) part[blockIdx.x] = l[0];
}

__global__ void scan_part_k(int* __restrict__ part, int nb) {  // 1 block, 512 thr
  __shared__ int l[512];
  int t = threadIdx.x;
  int v = (t < nb) ? part[t] : 0;
  l[t] = v;
  __syncthreads();
  for (int o = 1; o < 512; o <<= 1) {
    int a = (t >= o) ? l[t - o] : 0;
    __syncthreads();
    l[t] += a;
    __syncthreads();
  }
  if (t < nb) part[t] = l[t] - v;  // exclusive
}

__global__ void scan_final_k(const int* __restrict__ v, const int* __restrict__ part,
                             int* __restrict__ off, int n) {
  __shared__ int l[256];
  int t = threadIdx.x;
  int i = blockIdx.x * 256 + t;
  int x = (i < n) ? v[i] : 0;
  l[t] = x;
  __syncthreads();
  for (int o = 1; o < 256; o <<= 1) {
    int a = (t >= o) ? l[t - o] : 0;
    __syncthreads();
    l[t] += a;
    __syncthreads();
  }
  if (i < n) off[i] = l[t] - x + part[blockIdx.x];
}

// Per edge: claim slot in dst's bucket, store src. Bucket order irrelevant.
__global__ void fill_struct_k(const int* __restrict__ ei, const int* __restrict__ off,
                              int* __restrict__ cnt, int* __restrict__ csr_src,
                              int E, int N) {
  int e = blockIdx.x * blockDim.x + threadIdx.x;
  if (e >= E + N) return;
  int s, d;
  if (e < E) { s = ei[e]; d = ei[E + e]; }
  else       { s = e - E; d = s; }
  csr_src[off[d] + atomicAdd(cnt + d, 1)] = s;
}

// Alpha pass over CSR: G=D/4 lanes per dst node; lane c holds h[dst] chunk c.
template <int D>
__global__ void alpha_csr_k(const int* __restrict__ csr_src, const int* __restrict__ off,
                            const int* __restrict__ indeg, const float* __restrict__ h,
                            unsigned char* __restrict__ flagb, int* __restrict__ pos, int N) {
  const int G = D / 4;
  int t = blockIdx.x * 256 + threadIdx.x;
  int node = t / G;
  int c = t & (G - 1);
  if (node >= N) return;
  const float4 hd = *(const float4*)(h + (size_t)node * D + c * 4);
  int j = off[node];
  int je = j + indeg[node];
  for (; j < je; ++j) {
    int s = csr_src[j];  // same addr across G lanes -> broadcast
    float4 hs = *(const float4*)(h + (size_t)s * D + c * 4);
    float p = fmaf(hs.x, hd.x, fmaf(hs.y, hd.y, fmaf(hs.z, hd.z, hs.w * hd.w)));
#pragma unroll
    for (int o = G / 2; o > 0; o >>= 1) p += __shfl_xor(p, o);
    if (c == 0) {
      bool pz = p > 0.f;
      flagb[j] = (unsigned char)pz;
      if (pz) atomicAdd(pos + s, 1);
    }
  }
}

__global__ void denom_k(const int* __restrict__ pos, const int* __restrict__ deg,
                        float* __restrict__ dinv, int N) {
  int i = blockIdx.x * blockDim.x + threadIdx.x;
  if (i >= N) return;
  int p = pos[i], dg = deg[i];
  dinv[i] = (p > 0) ? 1.f / ((float)p + (float)(dg - p) * EXPC)
                    : 1.f / (EXPC * (float)dg);
}

// Gather over CSR: G=D/4 lanes per node; acc starts at bias; one write per row.
// FUSE_LSM (D=16): 4-lane log-softmax in-register, writes final output.
template <int D, bool FUSE_LSM>
__global__ void gather_csr_k(const int* __restrict__ csr_src, const int* __restrict__ off,
                             const int* __restrict__ indeg,
                             const unsigned char* __restrict__ flagb,
                             const float* __restrict__ dinv, const float* __restrict__ h,
                             const float* __restrict__ b, float* __restrict__ outp, int N) {
  const int G = D / 4;
  int t = blockIdx.x * 256 + threadIdx.x;
  int node = t / G;
  int c = t & (G - 1);
  if (node >= N) return;
  float4 acc = *(const float4*)(b + c * 4);
  int j = off[node];
  int je = j + indeg[node];
  for (; j < je; ++j) {
    int s = csr_src[j];
    float w = (flagb[j] ? 1.f : EXPC) * dinv[s];
    float4 hv = *(const float4*)(h + (size_t)s * D + c * 4);
    acc.x = fmaf(w, hv.x, acc.x);
    acc.y = fmaf(w, hv.y, acc.y);
    acc.z = fmaf(w, hv.z, acc.z);
    acc.w = fmaf(w, hv.w, acc.w);
  }
  if (FUSE_LSM) {
    float m = fmaxf(fmaxf(acc.x, acc.y), fmaxf(acc.z, acc.w));
    m = fmaxf(m, __shfl_xor(m, 1));
    m = fmaxf(m, __shfl_xor(m, 2));
    float s = expf(acc.x - m) + expf(acc.y - m) + expf(acc.z - m) + expf(acc.w - m);
    s += __shfl_xor(s, 1);
    s += __shfl_xor(s, 2);
    float lse = m + logf(s);
    acc.x -= lse; acc.y -= lse; acc.z -= lse; acc.w -= lse;
  }
  *(float4*)(outp + (size_t)node * D + c * 4) = acc;
}

extern "C" void kernel_launch(void* const* d_in, const int* in_sizes, int n_in,
                              void* d_out, int out_size, void* d_ws, size_t ws_size,
                              hipStream_t stream) {
  const float* x = (const float*)d_in[0];
  const int* ei = (const int*)d_in[1];
  const float* W1 = (const float*)d_in[2];
  const float* b1 = (const float*)d_in[3];
  const float* W2 = (const float*)d_in[4];
  const float* b2 = (const float*)d_in[5];
  float* out = (float*)d_out;

  const int N = in_sizes[0] / 64;
  const int E = in_sizes[1] / 2;
  const int Et = E + N;
  const int B = 256;
  const int nbN = (N + B - 1) / B;  // 391 for N=100k; scan assumes <=512
  const int nbE = (Et + B - 1) / B;
  const int nbT = (N + 63) / 64;    // 64-row GEMM tiles

  // Workspace (~63 MB).
  char* ws = (char*)d_ws;
  float* h1 = (float*)ws;      ws += (size_t)N * 64 * 4;  // 25.6 MB
  float* agg1 = (float*)ws;    ws += (size_t)N * 64 * 4;  // 25.6 MB
  int* deg = (int*)ws;         ws += (size_t)N * 4;       // [deg|in_deg|pos|cnt]
  int* in_deg = (int*)ws;      ws += (size_t)N * 4;
  int* pos = (int*)ws;         ws += (size_t)N * 4;
  int* cnt = (int*)ws;         ws += (size_t)N * 4;
  int* off = (int*)ws;         ws += (size_t)N * 4;
  float* dinv = (float*)ws;    ws += (size_t)N * 4;
  int* part = (int*)ws;        ws += 512 * 4;
  int* csr_src = (int*)ws;     ws += (size_t)Et * 4;      // 6.8 MB
  unsigned char* flagb = (unsigned char*)ws; ws += (size_t)Et;
  float* h2 = h1;  // alias: h1 dead once gather1 completes

  // ---- CSR structure (data-independent, built once) ----
  hipLaunchKernelGGL(zero_i32, dim3((4 * N + B - 1) / B), dim3(B), 0, stream, deg, 4 * N);
  hipLaunchKernelGGL(hist_k, dim3(nbE), dim3(B), 0, stream, ei, deg, in_deg, E, N);
  hipLaunchKernelGGL(scan_reduce_k, dim3(nbN), dim3(B), 0, stream, in_deg, part, N);
  hipLaunchKernelGGL(scan_part_k, dim3(1), dim3(512), 0, stream, part, nbN);
  hipLaunchKernelGGL(scan_final_k, dim3(nbN), dim3(B), 0, stream, in_deg, part, off, N);
  hipLaunchKernelGGL(fill_struct_k, dim3(nbE), dim3(B), 0, stream, ei, off, cnt, csr_src, E, N);

  // ---- layer 1 (D=64) ----
  hipLaunchKernelGGL((gemm64_k<false>), dim3(nbT), dim3(B), 0, stream, x, W1, h1, N);
  hipLaunchKernelGGL((alpha_csr_k<64>), dim3(((size_t)N * 16 + B - 1) / B), dim3(B), 0,
                     stream, csr_src, off, in_deg, h1, flagb, pos, N);
  hipLaunchKernelGGL(denom_k, dim3(nbN), dim3(B), 0, stream, pos, deg, dinv, N);
  hipLaunchKernelGGL((gather_csr_k<64, false>), dim3(((size_t)N * 16 + B - 1) / B), dim3(B),
                     0, stream, csr_src, off, in_deg, flagb, dinv, h1, b1, agg1, N);

  // ---- layer 2 (D=16): relu folded into gemm load, log-softmax fused ----
  hipLaunchKernelGGL(zero_i32, dim3(nbN), dim3(B), 0, stream, pos, N);
  hipLaunchKernelGGL((gemm16_k<true>), dim3(nbT), dim3(B), 0, stream, agg1, W2, h2, N);
  hipLaunchKernelGGL((alpha_csr_k<16>), dim3(((size_t)N * 4 + B - 1) / B), dim3(B), 0,
                     stream, csr_src, off, in_deg, h2, flagb, pos, N);
  hipLaunchKernelGGL(denom_k, dim3(nbN), dim3(B), 0, stream, pos, deg, dinv, N);
  hipLaunchKernelGGL((gather_csr_k<16, true>), dim3(((size_t)N * 4 + B - 1) / B), dim3(B),
                     0, stream, csr_src, off, in_deg, flagb, dinv, h2, b2, out, N);
}